// Round 7
// baseline (145.689 us; speedup 1.0000x reference)
//
#include <hip/hip_runtime.h>

// ScaledDotProductAttention B=8, L=2048, D=64, fp32 in/out.
//
// R20: zero-LDS frag-stream (R18 base) + two issued-byte dedupes at 4 w/SIMD.
// Evidence: R6 counters killed LDS staging (attn_shared 51us, all pipes idle,
// barrier-burst latency). Plateau model over R0/R4/R18: attn time ~= ISSUED
// VMEM bytes / ~10 TB/s IF 4 waves/SIMD (R4's byte-halving lost to 2 w/SIMD).
// R18 issued ~301 MB (K 134 + V 134 + Q 33). R20 issues ~205 MB:
//   (1) d-split: wave = kg(8 key slices of 256) x dh(2 output-dim halves),
//       qf=4 (the block's full 64 queries per wave). V loads halve (each dh
//       wave reads its 2 of 4 V planes -> 67 MB); QK^T duplicated per dh
//       (MFMA ~9% busy - free); ofr shrinks to [4][2] so qf=4 fits <=128
//       VGPR at 1024 thr -> 4 waves/SIMD preserved.
//   (2) Q via LDS: one coalesced 16 KB fp32 tile load + barrier, each wave
//       builds bq[4][2] from LDS (Q global reads 67 -> 4 MB).
// Hot loop unchanged otherwise: K frags dbuf one tile ahead, V same-tile
// (covered by QK+softmax), swapped QK^T -> exp2(folded 0.125*log2e) ->
// packed half4 P as B-frag of mfma_16x16x16f16, ks-paired V A-frags.
// Epilogue: 4 qf rounds over LDS; waves 0-3 combine kg(8) for one (dh,d)
// dim-quarter each; float4 stores. Numerics bit-identical to R18.
// Fallback: proven R3 kernel if ws too small.

#define B_ 8
#define L_ 2048
#define D_ 64
#define NT 256

typedef _Float16 half8_t __attribute__((ext_vector_type(8)));
typedef _Float16 half4_t __attribute__((ext_vector_type(4)));
typedef float f32x4 __attribute__((ext_vector_type(4)));

#define SCALE_LOG2E 0.1803368801111244f   // 0.125 * log2(e)

// ------------------------------------------------------------ prepass_frag --
// blocks 0..511: K fragments; 512..1023: V^T fragments. XCD-aligned batches.
__global__ __launch_bounds__(NT) void prepass_frag(
    const float* __restrict__ K, const float* __restrict__ V,
    _Float16* __restrict__ K16F, _Float16* __restrict__ VT16F)
{
    const int blk = blockIdx.x;
    const int t = threadIdx.x;
    if (blk < 512) {
        const int b  = blk & 7;           // XCD-aligned (blk%8 -> XCD)
        const int kt = blk >> 3;          // 0..63
        const int p    = t >> 6;          // plane = s*2 + c
        const int lane = t & 63;
        const int quad = lane >> 4;
        const int l15  = lane & 15;
        const int s = p >> 1, c = p & 1;
        const int row = kt * 32 + s * 16 + l15;
        const float* kp = K + ((size_t)b * L_ + row) * D_ + c * 32 + quad * 8;
        const float4 f0 = *(const float4*)kp;
        const float4 f1 = *(const float4*)(kp + 4);
        half8_t w;
        w[0] = (_Float16)f0.x; w[1] = (_Float16)f0.y;
        w[2] = (_Float16)f0.z; w[3] = (_Float16)f0.w;
        w[4] = (_Float16)f1.x; w[5] = (_Float16)f1.y;
        w[6] = (_Float16)f1.z; w[7] = (_Float16)f1.w;
        *(half8_t*)&K16F[((size_t)(b * 64 + kt) * 4 + p) * 512 + lane * 8] = w;
    } else {
        const int vb = blk - 512;
        const int b  = vb & 7;            // XCD-aligned
        const int kt = vb >> 3;
        #pragma unroll
        for (int i = 0; i < 2; ++i) {
            const int slot = i * NT + t;      // 512 slots = 8 planes x 64 lanes
            const int p    = slot >> 6;       // plane = d*2 + ks
            const int lane = slot & 63;
            const int quad = lane >> 4;
            const int l15  = lane & 15;
            const int d = p >> 1, ks = p & 1;
            const int row = kt * 32 + ks * 16 + quad * 4;
            const int col = d * 16 + l15;
            const float* vp = V + ((size_t)b * L_ + row) * D_ + col;
            half4_t a;
            a[0] = (_Float16)vp[0];
            a[1] = (_Float16)vp[D_];
            a[2] = (_Float16)vp[2 * D_];
            a[3] = (_Float16)vp[3 * D_];
            // ks-paired layout: one b128 per (tile, d-plane) at consume time
            *(half4_t*)&VT16F[((size_t)(b * 64 + kt) * 4 + d) * 512 + lane * 8 + ks * 4] = a;
        }
    }
}

// ------------------------------------------------------------- attn_dsplit --

#define LOADK(KT, BK)                                                           \
    {                                                                           \
        const int ktc_ = (KT) & 63;                                             \
        _Pragma("unroll") for (int s = 0; s < 2; ++s)                           \
        _Pragma("unroll") for (int c = 0; c < 2; ++c)                           \
            BK[s][c] = *(const half8_t*)&KbF[((size_t)ktc_ * 4 + s * 2 + c) * 512 + lane * 8]; \
    }

// dh wave loads only its 2 of 4 V d-planes
#define LOADV(KT, AV)                                                           \
    {                                                                           \
        const int ktc_ = (KT) & 63;                                             \
        _Pragma("unroll") for (int j = 0; j < 2; ++j)                           \
            AV[j] = *(const half8_t*)&VbF[((size_t)ktc_ * 4 + dh * 2 + j) * 512 + lane * 8]; \
    }

// qf split in pairs to cap live registers (pb is 8 regs per pair)
#define PROC(BK, AV)                                                            \
    _Pragma("unroll") for (int qp = 0; qp < 2; ++qp) {                          \
        half4_t pb[2][2];                                                       \
        _Pragma("unroll") for (int ks = 0; ks < 2; ++ks)                        \
        _Pragma("unroll") for (int q2 = 0; q2 < 2; ++q2) {                      \
            const int qf = qp * 2 + q2;                                         \
            f32x4 acc = (f32x4){0.f, 0.f, 0.f, 0.f};                            \
            acc = __builtin_amdgcn_mfma_f32_16x16x32_f16(BK[ks][0], bq[qf][0], acc, 0, 0, 0); \
            acc = __builtin_amdgcn_mfma_f32_16x16x32_f16(BK[ks][1], bq[qf][1], acc, 0, 0, 0); \
            const float p0 = __builtin_exp2f(acc[0]);                           \
            const float p1 = __builtin_exp2f(acc[1]);                           \
            const float p2 = __builtin_exp2f(acc[2]);                           \
            const float p3 = __builtin_exp2f(acc[3]);                           \
            lacc[qf] += (p0 + p1) + (p2 + p3);                                  \
            half4_t pv;                                                         \
            pv[0] = (_Float16)p0; pv[1] = (_Float16)p1;                         \
            pv[2] = (_Float16)p2; pv[3] = (_Float16)p3;                         \
            pb[ks][q2] = pv;                                                    \
        }                                                                       \
        _Pragma("unroll") for (int j = 0; j < 2; ++j) {                         \
            const half4_t alo = __builtin_shufflevector(AV[j], AV[j], 0, 1, 2, 3); \
            const half4_t ahi = __builtin_shufflevector(AV[j], AV[j], 4, 5, 6, 7); \
            _Pragma("unroll") for (int q2 = 0; q2 < 2; ++q2) {                  \
                const int qf = qp * 2 + q2;                                     \
                ofr[qf][j] = __builtin_amdgcn_mfma_f32_16x16x16f16(alo, pb[0][q2], ofr[qf][j], 0, 0, 0); \
                ofr[qf][j] = __builtin_amdgcn_mfma_f32_16x16x16f16(ahi, pb[1][q2], ofr[qf][j], 0, 0, 0); \
            }                                                                   \
        }                                                                       \
    }

__global__ __launch_bounds__(1024) void attn_dsplit(
    const float* __restrict__ Q,
    const _Float16* __restrict__ K16F,
    const _Float16* __restrict__ VT16F,
    float* __restrict__ O)
{
    // Prologue: QL = fp32 Q tile [64][68] (17408 B).
    // Epilogue: Ored [16*64][9] (9216 f) + Lred [512] = 38912 B. Shared pool.
    __shared__ __align__(16) float SH[9728];

    const int t    = threadIdx.x;
    const int wave = t >> 6;                   // 0..15
    const int lane = t & 63;
    const int quad = lane >> 4;
    const int l15  = lane & 15;
    const int kg   = wave >> 1;                // key range [kg*256, +256)
    const int dh   = wave & 1;                 // output-dim half (32 dims)

    const int b   = blockIdx.x & 7;            // batch <-> XCD affinity
    const int qbi = blockIdx.x >> 3;           // query block 0..31
    const int qb  = qbi * 64;
    const int kt0 = kg * 8;                    // wave's 8 tiles (256 keys)

    const _Float16* KbF = K16F + (size_t)b * 64 * 4 * 512;
    const _Float16* VbF = VT16F + (size_t)b * 64 * 4 * 512;

    // ---- Q tile -> LDS (one coalesced 16 KB block load, fp32) -------------
    {
        const int qr = t >> 4;                 // 0..63
        const int c4 = t & 15;                 // 0..15
        const float4 qv = *(const float4*)&Q[((size_t)b * L_ + qb + qr) * D_ + c4 * 4];
        *(float4*)&SH[qr * 68 + c4 * 4] = qv;
    }
    __syncthreads();

    // ---- bq[4][2] from LDS, scaled by 0.125*log2(e) ------------------------
    half8_t bq[4][2];
    #pragma unroll
    for (int qf = 0; qf < 4; ++qf) {
        const float* qp = &SH[(qf * 16 + l15) * 68 + quad * 8];
        #pragma unroll
        for (int c = 0; c < 2; ++c) {
            const float4 f0 = *(const float4*)(qp + c * 32);
            const float4 f1 = *(const float4*)(qp + c * 32 + 4);
            bq[qf][c][0] = (_Float16)(f0.x * SCALE_LOG2E);
            bq[qf][c][1] = (_Float16)(f0.y * SCALE_LOG2E);
            bq[qf][c][2] = (_Float16)(f0.z * SCALE_LOG2E);
            bq[qf][c][3] = (_Float16)(f0.w * SCALE_LOG2E);
            bq[qf][c][4] = (_Float16)(f1.x * SCALE_LOG2E);
            bq[qf][c][5] = (_Float16)(f1.y * SCALE_LOG2E);
            bq[qf][c][6] = (_Float16)(f1.z * SCALE_LOG2E);
            bq[qf][c][7] = (_Float16)(f1.w * SCALE_LOG2E);
        }
    }

    f32x4 ofr[4][2];
    #pragma unroll
    for (int qf = 0; qf < 4; ++qf)
        #pragma unroll
        for (int j = 0; j < 2; ++j)
            ofr[qf][j] = (f32x4){0.f, 0.f, 0.f, 0.f};
    float lacc[4] = {0.f, 0.f, 0.f, 0.f};

    // ---- hot loop: 8 tiles of 32 keys; K dbuf one ahead, V same-tile ------
    half8_t bkA[2][2], bkB[2][2], av[2];
    LOADK(kt0, bkA);
    for (int it = 0; it < 4; ++it) {
        const int kta = kt0 + it * 2;
        LOADK(kta + 1, bkB);
        LOADV(kta, av);           // covered by QK+softmax inside PROC
        PROC(bkA, av);
        LOADK(kta + 2, bkA);      // tile index clamped (&63) inside macro
        LOADV(kta + 1, av);
        PROC(bkB, av);
    }

    // ---- l: reduce over quads (lane holds partial for query qf*16+l15) ----
    float lsum[4];
    #pragma unroll
    for (int qf = 0; qf < 4; ++qf) {
        float v = lacc[qf];
        v += __shfl_xor(v, 16, 64);
        v += __shfl_xor(v, 32, 64);
        lsum[qf] = v;
    }
    float* Ored = &SH[0];                      // [16 waves][64 lanes][9]
    float* Lred = &SH[9216];                   // [8 kg][64]
    if (quad == 0 && dh == 0) {
        #pragma unroll
        for (int qf = 0; qf < 4; ++qf)
            Lred[kg * 64 + qf * 16 + l15] = lsum[qf];
    }

    // ---- cross-wave combine: 4 qf rounds; waves 0-3 each own a dim quarter -
    #pragma unroll
    for (int qf = 0; qf < 4; ++qf) {
        __syncthreads();   // previous round's reads (and Lred writes) done
        float* dst = &Ored[(wave * 64 + lane) * 9];
        #pragma unroll
        for (int j = 0; j < 2; ++j)
            #pragma unroll
            for (int r = 0; r < 4; ++r)
                dst[j * 4 + r] = ofr[qf][j][r];
        __syncthreads();
        if (wave < 4) {
            const int dhr = wave & 1;           // dim half
            const int dr  = wave >> 1;          // d-plane within half
            float lt = 0.f;
            #pragma unroll
            for (int k2 = 0; k2 < 8; ++k2)
                lt += Lred[k2 * 64 + qf * 16 + l15];
            const float inv = 1.0f / lt;
            f32x4 osum = (f32x4){0.f, 0.f, 0.f, 0.f};
            #pragma unroll
            for (int k2 = 0; k2 < 8; ++k2) {
                const float* src = &Ored[((k2 * 2 + dhr) * 64 + lane) * 9 + dr * 4];
                osum[0] += src[0]; osum[1] += src[1];
                osum[2] += src[2]; osum[3] += src[3];
            }
            float4 outv;
            outv.x = osum[0] * inv; outv.y = osum[1] * inv;
            outv.z = osum[2] * inv; outv.w = osum[3] * inv;
            // query = qb + qf*16 + l15 ; dims = dhr*32 + dr*16 + quad*4 .. +4
            *(float4*)&O[((size_t)b * L_ + qb + qf * 16 + l15) * D_
                         + dhr * 32 + dr * 16 + quad * 4] = outv;
        }
    }
}

// ------------------------------------------------- fallback (R3, no ws) ----
#define KS 72
__global__ __launch_bounds__(NT) void attn_mfma_f16(
    const float* __restrict__ Q, const float* __restrict__ K,
    const float* __restrict__ V, float* __restrict__ O)
{
    __shared__ __align__(16) _Float16 Kt[64 * KS];
    __shared__ __align__(16) _Float16 Vt[D_ * KS];
    __shared__ __align__(16) _Float16 Pt[4][16 * KS];

    const int t = threadIdx.x;
    const int wave = t >> 6, lane = t & 63, quad = lane >> 4, l15 = lane & 15;
    const int bpb = L_ / 64;
    const int b = blockIdx.x / bpb;
    const int qb = (blockIdx.x % bpb) * 64 + wave * 16;
    const size_t boff = (size_t)b * L_ * D_;

    half8_t aq[2];
    {
        const float* qp = Q + boff + (size_t)(qb + l15) * D_ + quad * 8;
        #pragma unroll
        for (int c = 0; c < 2; ++c) {
            const float4* p4 = (const float4*)(qp + c * 32);
            const float4 f0 = p4[0], f1 = p4[1];
            aq[c][0] = (_Float16)f0.x; aq[c][1] = (_Float16)f0.y;
            aq[c][2] = (_Float16)f0.z; aq[c][3] = (_Float16)f0.w;
            aq[c][4] = (_Float16)f1.x; aq[c][5] = (_Float16)f1.y;
            aq[c][6] = (_Float16)f1.z; aq[c][7] = (_Float16)f1.w;
        }
    }
    f32x4 ofr[4];
    #pragma unroll
    for (int d = 0; d < 4; ++d) ofr[d] = (f32x4){0.f, 0.f, 0.f, 0.f};
    float lacc[4] = {0.f, 0.f, 0.f, 0.f};
    const int skey = t & 63, sdg = t >> 6;
    _Float16* Pw = &Pt[wave][0];

    for (int kt = 0; kt < L_ / 64; ++kt) {
        __syncthreads();
        {
            const float4* kg4 = (const float4*)(K + boff + (size_t)(kt * 64 + skey) * D_ + sdg * 16);
            const float4 f0 = kg4[0], f1 = kg4[1], f2 = kg4[2], f3 = kg4[3];
            half8_t w0, w1;
            w0[0] = (_Float16)f0.x; w0[1] = (_Float16)f0.y;
            w0[2] = (_Float16)f0.z; w0[3] = (_Float16)f0.w;
            w0[4] = (_Float16)f1.x; w0[5] = (_Float16)f1.y;
            w0[6] = (_Float16)f1.z; w0[7] = (_Float16)f1.w;
            w1[0] = (_Float16)f2.x; w1[1] = (_Float16)f2.y;
            w1[2] = (_Float16)f2.z; w1[3] = (_Float16)f2.w;
            w1[4] = (_Float16)f3.x; w1[5] = (_Float16)f3.y;
            w1[6] = (_Float16)f3.z; w1[7] = (_Float16)f3.w;
            *(half8_t*)&Kt[skey * KS + sdg * 16] = w0;
            *(half8_t*)&Kt[skey * KS + sdg * 16 + 8] = w1;
        }
        {
            const float4* vg4 = (const float4*)(V + boff + (size_t)(kt * 64 + skey) * D_ + sdg * 16);
            #pragma unroll
            for (int i = 0; i < 4; ++i) {
                const float4 f = vg4[i];
                const int d0 = sdg * 16 + i * 4;
                Vt[(d0 + 0) * KS + skey] = (_Float16)f.x;
                Vt[(d0 + 1) * KS + skey] = (_Float16)f.y;
                Vt[(d0 + 2) * KS + skey] = (_Float16)f.z;
                Vt[(d0 + 3) * KS + skey] = (_Float16)f.w;
            }
        }
        __syncthreads();
        #pragma unroll
        for (int s = 0; s < 4; ++s) {
            const half8_t bk0 = *(const half8_t*)&Kt[(s * 16 + l15) * KS + quad * 8];
            const half8_t bk1 = *(const half8_t*)&Kt[(s * 16 + l15) * KS + 32 + quad * 8];
            f32x4 sc = (f32x4){0.f, 0.f, 0.f, 0.f};
            sc = __builtin_amdgcn_mfma_f32_16x16x32_f16(aq[0], bk0, sc, 0, 0, 0);
            sc = __builtin_amdgcn_mfma_f32_16x16x32_f16(aq[1], bk1, sc, 0, 0, 0);
            #pragma unroll
            for (int r = 0; r < 4; ++r) {
                const float p = __expf(sc[r] * 0.125f);
                lacc[r] += p;
                Pw[(quad * 4 + r) * KS + s * 16 + l15] = (_Float16)p;
            }
        }
        __syncthreads();
        #pragma unroll
        for (int c = 0; c < 2; ++c) {
            const half8_t ap = *(const half8_t*)&Pw[l15 * KS + c * 32 + quad * 8];
            #pragma unroll
            for (int d = 0; d < 4; ++d) {
                const half8_t bv = *(const half8_t*)&Vt[(d * 16 + l15) * KS + c * 32 + quad * 8];
                ofr[d] = __builtin_amdgcn_mfma_f32_16x16x32_f16(ap, bv, ofr[d], 0, 0, 0);
            }
        }
    }
    #pragma unroll
    for (int r = 0; r < 4; ++r) {
        float v = lacc[r];
        v += __shfl_xor(v, 1, 64);
        v += __shfl_xor(v, 2, 64);
        v += __shfl_xor(v, 4, 64);
        v += __shfl_xor(v, 8, 64);
        lacc[r] = v;
    }
    #pragma unroll
    for (int r = 0; r < 4; ++r) {
        const float inv = 1.0f / lacc[r];
        float* orow = O + boff + (size_t)(qb + quad * 4 + r) * D_ + l15;
        #pragma unroll
        for (int d = 0; d < 4; ++d) orow[d * 16] = ofr[d][r] * inv;
    }
}

extern "C" void kernel_launch(void* const* d_in, const int* in_sizes, int n_in,
                              void* d_out, int out_size, void* d_ws, size_t ws_size,
                              hipStream_t stream) {
    const float* Q = (const float*)d_in[0];
    const float* K = (const float*)d_in[1];
    const float* V = (const float*)d_in[2];
    float* O = (float*)d_out;

    if (ws_size >= (size_t)8 * 1024 * 1024) {
        _Float16* K16F  = (_Float16*)d_ws;                             // 2 MB
        _Float16* VT16F = K16F + (size_t)1048576;                      // 2 MB
        prepass_frag<<<1024, NT, 0, stream>>>(K, V, K16F, VT16F);
        attn_dsplit<<<256, 1024, 0, stream>>>(Q, K16F, VT16F, O);
    } else {
        attn_mfma_f16<<<256, NT, 0, stream>>>(Q, K, V, O);
    }
}

// Round 8
// 95.448 us; speedup vs baseline: 1.5264x; 1.5264x over previous
//
#include <hip/hip_runtime.h>

// ScaledDotProductAttention B=8, L=2048, D=64, fp32 in/out.
//
// R21 = R20 (d-split dedupe; verified CORRECT) with the spill root-caused and
// fixed. R7 counters: VGPR_Count=64 (compiler targeted 8 w/SIMD since LDS
// allowed 2 blk/CU) -> ~70 regs spilled -> FETCH 107 MB / WRITE 168 MB of
// scratch traffic -> 85 us. Fixes:
//   (1) __launch_bounds__(1024, 4): 4 waves/SIMD min -> VGPR cap 128.
//   (2) Q lives in LDS as pre-converted, pre-scaled f16 B-frags (8 KB,
//       prepass-K-style layout). Hot loop reads bq per qf-pair per tile
//       (8x ds_read_b128/tile, ~100cy, covered) -> 32 persistent VGPRs freed;
//       worst-case live ~120 <= 128. Q global reads 67 -> 4 MB.
//   (3) PROC consumes ks-slices sequentially (halves pb/acc live windows).
// Structure (R20): 256 blocks = b(8) x qblock(32 of 64 q); 1024 thr = 16
// waves = kg(8 key slices of 256) x dh(2 output-dim halves). V loads halved
// per dh (67 MB); K dbuf one tile ahead (134 MB); issued ~205 MB total vs
// R18's 301 at the same 4 w/SIMD. Consume math = verified swapped-QK^T ->
// exp2(0.125*log2e folded into Q) -> packed half4 P as B-frag of
// mfma_16x16x16f16 -> ks-paired V A-frags. Epilogue = R20 verbatim
// (passed absmax): 4 qf rounds, waves 0-3 combine kg(8) per dim-quarter.
// Fallback: proven R3 kernel if ws too small.

#define B_ 8
#define L_ 2048
#define D_ 64
#define NT 256

typedef _Float16 half8_t __attribute__((ext_vector_type(8)));
typedef _Float16 half4_t __attribute__((ext_vector_type(4)));
typedef float f32x4 __attribute__((ext_vector_type(4)));

#define SCALE_LOG2E 0.1803368801111244f   // 0.125 * log2(e)

// ------------------------------------------------------------ prepass_frag --
// blocks 0..511: K fragments; 512..1023: V^T fragments. XCD-aligned batches.
__global__ __launch_bounds__(NT) void prepass_frag(
    const float* __restrict__ K, const float* __restrict__ V,
    _Float16* __restrict__ K16F, _Float16* __restrict__ VT16F)
{
    const int blk = blockIdx.x;
    const int t = threadIdx.x;
    if (blk < 512) {
        const int b  = blk & 7;           // XCD-aligned (blk%8 -> XCD)
        const int kt = blk >> 3;          // 0..63
        const int p    = t >> 6;          // plane = s*2 + c
        const int lane = t & 63;
        const int quad = lane >> 4;
        const int l15  = lane & 15;
        const int s = p >> 1, c = p & 1;
        const int row = kt * 32 + s * 16 + l15;
        const float* kp = K + ((size_t)b * L_ + row) * D_ + c * 32 + quad * 8;
        const float4 f0 = *(const float4*)kp;
        const float4 f1 = *(const float4*)(kp + 4);
        half8_t w;
        w[0] = (_Float16)f0.x; w[1] = (_Float16)f0.y;
        w[2] = (_Float16)f0.z; w[3] = (_Float16)f0.w;
        w[4] = (_Float16)f1.x; w[5] = (_Float16)f1.y;
        w[6] = (_Float16)f1.z; w[7] = (_Float16)f1.w;
        *(half8_t*)&K16F[((size_t)(b * 64 + kt) * 4 + p) * 512 + lane * 8] = w;
    } else {
        const int vb = blk - 512;
        const int b  = vb & 7;            // XCD-aligned
        const int kt = vb >> 3;
        #pragma unroll
        for (int i = 0; i < 2; ++i) {
            const int slot = i * NT + t;      // 512 slots = 8 planes x 64 lanes
            const int p    = slot >> 6;       // plane = d*2 + ks
            const int lane = slot & 63;
            const int quad = lane >> 4;
            const int l15  = lane & 15;
            const int d = p >> 1, ks = p & 1;
            const int row = kt * 32 + ks * 16 + quad * 4;
            const int col = d * 16 + l15;
            const float* vp = V + ((size_t)b * L_ + row) * D_ + col;
            half4_t a;
            a[0] = (_Float16)vp[0];
            a[1] = (_Float16)vp[D_];
            a[2] = (_Float16)vp[2 * D_];
            a[3] = (_Float16)vp[3 * D_];
            // ks-paired layout: one b128 per (tile, d-plane) at consume time
            *(half4_t*)&VT16F[((size_t)(b * 64 + kt) * 4 + d) * 512 + lane * 8 + ks * 4] = a;
        }
    }
}

// ------------------------------------------------------------ attn_dsplit2 --

#define LOADK(KT, BK)                                                           \
    {                                                                           \
        const int ktc_ = (KT) & 63;                                             \
        _Pragma("unroll") for (int s = 0; s < 2; ++s)                           \
        _Pragma("unroll") for (int c = 0; c < 2; ++c)                           \
            BK[s][c] = *(const half8_t*)&KbF[((size_t)ktc_ * 4 + s * 2 + c) * 512 + lane * 8]; \
    }

// dh wave loads only its 2 of 4 V d-planes
#define LOADV(KT, AV)                                                           \
    {                                                                           \
        const int ktc_ = (KT) & 63;                                             \
        _Pragma("unroll") for (int j = 0; j < 2; ++j)                           \
            AV[j] = *(const half8_t*)&VbF[((size_t)ktc_ * 4 + dh * 2 + j) * 512 + lane * 8]; \
    }

// per qf-pair: bq from LDS (16 regs window); ks-slices sequential (pb[2] only)
#define PROC(BK, AV)                                                            \
    _Pragma("unroll") for (int qp = 0; qp < 2; ++qp) {                          \
        half8_t bqp[2][2];                                                      \
        _Pragma("unroll") for (int q2 = 0; q2 < 2; ++q2)                        \
        _Pragma("unroll") for (int c = 0; c < 2; ++c)                           \
            bqp[q2][c] = *(const half8_t*)&QF[((qp * 2 + q2) * 2 + c) * 512 + lane * 8]; \
        _Pragma("unroll") for (int ks = 0; ks < 2; ++ks) {                      \
            half4_t pb[2];                                                      \
            _Pragma("unroll") for (int q2 = 0; q2 < 2; ++q2) {                  \
                const int qf = qp * 2 + q2;                                     \
                f32x4 acc = (f32x4){0.f, 0.f, 0.f, 0.f};                        \
                acc = __builtin_amdgcn_mfma_f32_16x16x32_f16(BK[ks][0], bqp[q2][0], acc, 0, 0, 0); \
                acc = __builtin_amdgcn_mfma_f32_16x16x32_f16(BK[ks][1], bqp[q2][1], acc, 0, 0, 0); \
                const float p0 = __builtin_exp2f(acc[0]);                       \
                const float p1 = __builtin_exp2f(acc[1]);                       \
                const float p2 = __builtin_exp2f(acc[2]);                       \
                const float p3 = __builtin_exp2f(acc[3]);                       \
                lacc[qf] += (p0 + p1) + (p2 + p3);                              \
                half4_t pv;                                                     \
                pv[0] = (_Float16)p0; pv[1] = (_Float16)p1;                     \
                pv[2] = (_Float16)p2; pv[3] = (_Float16)p3;                     \
                pb[q2] = pv;                                                    \
            }                                                                   \
            _Pragma("unroll") for (int j = 0; j < 2; ++j) {                     \
                const half4_t aks = (ks == 0)                                   \
                    ? __builtin_shufflevector(AV[j], AV[j], 0, 1, 2, 3)         \
                    : __builtin_shufflevector(AV[j], AV[j], 4, 5, 6, 7);        \
                _Pragma("unroll") for (int q2 = 0; q2 < 2; ++q2)                \
                    ofr[qp * 2 + q2][j] = __builtin_amdgcn_mfma_f32_16x16x16f16(aks, pb[q2], ofr[qp * 2 + q2][j], 0, 0, 0); \
            }                                                                   \
        }                                                                       \
    }

__global__ __launch_bounds__(1024, 4) void attn_dsplit2(
    const float* __restrict__ Q,
    const _Float16* __restrict__ K16F,
    const _Float16* __restrict__ VT16F,
    float* __restrict__ O)
{
    // Pool (38912 B): prologue/hot QF = f16 Q-frags (8 planes x 512 = 8 KB,
    // floats 0..2047). Epilogue: Ored floats 0..9215 (16w x 64l x 9; first
    // write is after a full-block barrier, so aliasing QF is safe) +
    // Lred floats 9216..9727 (disjoint from QF; written pre-barrier).
    __shared__ __align__(16) float SH[9728];
    _Float16* QF = (_Float16*)&SH[0];

    const int t    = threadIdx.x;
    const int wave = t >> 6;                   // 0..15
    const int lane = t & 63;
    const int quad = lane >> 4;
    const int l15  = lane & 15;
    const int kg   = wave >> 1;                // key range [kg*256, +256)
    const int dh   = wave & 1;                 // output-dim half (32 dims)

    const int b   = blockIdx.x & 7;            // batch <-> XCD affinity
    const int qbi = blockIdx.x >> 3;           // query block 0..31
    const int qb  = qbi * 64;
    const int kt0 = kg * 8;                    // wave's 8 tiles (256 keys)

    const _Float16* KbF = K16F + (size_t)b * 64 * 4 * 512;
    const _Float16* VbF = VT16F + (size_t)b * 64 * 4 * 512;

    // ---- Q -> LDS as f16 B-frags, pre-scaled (prepass-K math on Q) --------
    if (t < 512) {
        const int p  = t >> 6;                 // plane = qf*2 + c
        const int ln = t & 63;
        const int qd = ln >> 4;
        const int lq = ln & 15;
        const int qf = p >> 1, c = p & 1;
        const float* qp = Q + ((size_t)b * L_ + qb + qf * 16 + lq) * D_ + c * 32 + qd * 8;
        const float4 f0 = *(const float4*)qp;
        const float4 f1 = *(const float4*)(qp + 4);
        half8_t w;
        w[0] = (_Float16)(f0.x * SCALE_LOG2E);
        w[1] = (_Float16)(f0.y * SCALE_LOG2E);
        w[2] = (_Float16)(f0.z * SCALE_LOG2E);
        w[3] = (_Float16)(f0.w * SCALE_LOG2E);
        w[4] = (_Float16)(f1.x * SCALE_LOG2E);
        w[5] = (_Float16)(f1.y * SCALE_LOG2E);
        w[6] = (_Float16)(f1.z * SCALE_LOG2E);
        w[7] = (_Float16)(f1.w * SCALE_LOG2E);
        *(half8_t*)&QF[p * 512 + ln * 8] = w;
    }
    __syncthreads();

    f32x4 ofr[4][2];
    #pragma unroll
    for (int qf = 0; qf < 4; ++qf)
        #pragma unroll
        for (int j = 0; j < 2; ++j)
            ofr[qf][j] = (f32x4){0.f, 0.f, 0.f, 0.f};
    float lacc[4] = {0.f, 0.f, 0.f, 0.f};

    // ---- hot loop: 8 tiles of 32 keys; K dbuf one ahead, V same-tile ------
    half8_t bkA[2][2], bkB[2][2], av[2];
    LOADK(kt0, bkA);
    for (int it = 0; it < 4; ++it) {
        const int kta = kt0 + it * 2;
        LOADK(kta + 1, bkB);
        LOADV(kta, av);           // covered by QK+softmax inside PROC
        PROC(bkA, av);
        LOADK(kta + 2, bkA);      // tile index clamped (&63) inside macro
        LOADV(kta + 1, av);
        PROC(bkB, av);
    }

    // ---- l: reduce over quads (lane holds partial for query qf*16+l15) ----
    float lsum[4];
    #pragma unroll
    for (int qf = 0; qf < 4; ++qf) {
        float v = lacc[qf];
        v += __shfl_xor(v, 16, 64);
        v += __shfl_xor(v, 32, 64);
        lsum[qf] = v;
    }
    float* Ored = &SH[0];                      // [16 waves][64 lanes][9]
    float* Lred = &SH[9216];                   // [8 kg][64]
    if (quad == 0 && dh == 0) {
        #pragma unroll
        for (int qf = 0; qf < 4; ++qf)
            Lred[kg * 64 + qf * 16 + l15] = lsum[qf];
    }

    // ---- cross-wave combine: 4 qf rounds; waves 0-3 each own a dim quarter -
    #pragma unroll
    for (int qf = 0; qf < 4; ++qf) {
        __syncthreads();   // previous round's reads (and Lred writes) done
        float* dst = &Ored[(wave * 64 + lane) * 9];
        #pragma unroll
        for (int j = 0; j < 2; ++j)
            #pragma unroll
            for (int r = 0; r < 4; ++r)
                dst[j * 4 + r] = ofr[qf][j][r];
        __syncthreads();
        if (wave < 4) {
            const int dhr = wave & 1;           // dim half
            const int dr  = wave >> 1;          // d-plane within half
            float lt = 0.f;
            #pragma unroll
            for (int k2 = 0; k2 < 8; ++k2)
                lt += Lred[k2 * 64 + qf * 16 + l15];
            const float inv = 1.0f / lt;
            f32x4 osum = (f32x4){0.f, 0.f, 0.f, 0.f};
            #pragma unroll
            for (int k2 = 0; k2 < 8; ++k2) {
                const float* src = &Ored[((k2 * 2 + dhr) * 64 + lane) * 9 + dr * 4];
                osum[0] += src[0]; osum[1] += src[1];
                osum[2] += src[2]; osum[3] += src[3];
            }
            float4 outv;
            outv.x = osum[0] * inv; outv.y = osum[1] * inv;
            outv.z = osum[2] * inv; outv.w = osum[3] * inv;
            // query = qb + qf*16 + l15 ; dims = dhr*32 + dr*16 + quad*4 .. +4
            *(float4*)&O[((size_t)b * L_ + qb + qf * 16 + l15) * D_
                         + dhr * 32 + dr * 16 + quad * 4] = outv;
        }
    }
}

// ------------------------------------------------- fallback (R3, no ws) ----
#define KS 72
__global__ __launch_bounds__(NT) void attn_mfma_f16(
    const float* __restrict__ Q, const float* __restrict__ K,
    const float* __restrict__ V, float* __restrict__ O)
{
    __shared__ __align__(16) _Float16 Kt[64 * KS];
    __shared__ __align__(16) _Float16 Vt[D_ * KS];
    __shared__ __align__(16) _Float16 Pt[4][16 * KS];

    const int t = threadIdx.x;
    const int wave = t >> 6, lane = t & 63, quad = lane >> 4, l15 = lane & 15;
    const int bpb = L_ / 64;
    const int b = blockIdx.x / bpb;
    const int qb = (blockIdx.x % bpb) * 64 + wave * 16;
    const size_t boff = (size_t)b * L_ * D_;

    half8_t aq[2];
    {
        const float* qp = Q + boff + (size_t)(qb + l15) * D_ + quad * 8;
        #pragma unroll
        for (int c = 0; c < 2; ++c) {
            const float4* p4 = (const float4*)(qp + c * 32);
            const float4 f0 = p4[0], f1 = p4[1];
            aq[c][0] = (_Float16)f0.x; aq[c][1] = (_Float16)f0.y;
            aq[c][2] = (_Float16)f0.z; aq[c][3] = (_Float16)f0.w;
            aq[c][4] = (_Float16)f1.x; aq[c][5] = (_Float16)f1.y;
            aq[c][6] = (_Float16)f1.z; aq[c][7] = (_Float16)f1.w;
        }
    }
    f32x4 ofr[4];
    #pragma unroll
    for (int d = 0; d < 4; ++d) ofr[d] = (f32x4){0.f, 0.f, 0.f, 0.f};
    float lacc[4] = {0.f, 0.f, 0.f, 0.f};
    const int skey = t & 63, sdg = t >> 6;
    _Float16* Pw = &Pt[wave][0];

    for (int kt = 0; kt < L_ / 64; ++kt) {
        __syncthreads();
        {
            const float4* kg4 = (const float4*)(K + boff + (size_t)(kt * 64 + skey) * D_ + sdg * 16);
            const float4 f0 = kg4[0], f1 = kg4[1], f2 = kg4[2], f3 = kg4[3];
            half8_t w0, w1;
            w0[0] = (_Float16)f0.x; w0[1] = (_Float16)f0.y;
            w0[2] = (_Float16)f0.z; w0[3] = (_Float16)f0.w;
            w0[4] = (_Float16)f1.x; w0[5] = (_Float16)f1.y;
            w0[6] = (_Float16)f1.z; w0[7] = (_Float16)f1.w;
            w1[0] = (_Float16)f2.x; w1[1] = (_Float16)f2.y;
            w1[2] = (_Float16)f2.z; w1[3] = (_Float16)f2.w;
            w1[4] = (_Float16)f3.x; w1[5] = (_Float16)f3.y;
            w1[6] = (_Float16)f3.z; w1[7] = (_Float16)f3.w;
            *(half8_t*)&Kt[skey * KS + sdg * 16] = w0;
            *(half8_t*)&Kt[skey * KS + sdg * 16 + 8] = w1;
        }
        {
            const float4* vg4 = (const float4*)(V + boff + (size_t)(kt * 64 + skey) * D_ + sdg * 16);
            #pragma unroll
            for (int i = 0; i < 4; ++i) {
                const float4 f = vg4[i];
                const int d0 = sdg * 16 + i * 4;
                Vt[(d0 + 0) * KS + skey] = (_Float16)f.x;
                Vt[(d0 + 1) * KS + skey] = (_Float16)f.y;
                Vt[(d0 + 2) * KS + skey] = (_Float16)f.z;
                Vt[(d0 + 3) * KS + skey] = (_Float16)f.w;
            }
        }
        __syncthreads();
        #pragma unroll
        for (int s = 0; s < 4; ++s) {
            const half8_t bk0 = *(const half8_t*)&Kt[(s * 16 + l15) * KS + quad * 8];
            const half8_t bk1 = *(const half8_t*)&Kt[(s * 16 + l15) * KS + 32 + quad * 8];
            f32x4 sc = (f32x4){0.f, 0.f, 0.f, 0.f};
            sc = __builtin_amdgcn_mfma_f32_16x16x32_f16(aq[0], bk0, sc, 0, 0, 0);
            sc = __builtin_amdgcn_mfma_f32_16x16x32_f16(aq[1], bk1, sc, 0, 0, 0);
            #pragma unroll
            for (int r = 0; r < 4; ++r) {
                const float p = __expf(sc[r] * 0.125f);
                lacc[r] += p;
                Pw[(quad * 4 + r) * KS + s * 16 + l15] = (_Float16)p;
            }
        }
        __syncthreads();
        #pragma unroll
        for (int c = 0; c < 2; ++c) {
            const half8_t ap = *(const half8_t*)&Pw[l15 * KS + c * 32 + quad * 8];
            #pragma unroll
            for (int d = 0; d < 4; ++d) {
                const half8_t bv = *(const half8_t*)&Vt[(d * 16 + l15) * KS + c * 32 + quad * 8];
                ofr[d] = __builtin_amdgcn_mfma_f32_16x16x32_f16(ap, bv, ofr[d], 0, 0, 0);
            }
        }
    }
    #pragma unroll
    for (int r = 0; r < 4; ++r) {
        float v = lacc[r];
        v += __shfl_xor(v, 1, 64);
        v += __shfl_xor(v, 2, 64);
        v += __shfl_xor(v, 4, 64);
        v += __shfl_xor(v, 8, 64);
        lacc[r] = v;
    }
    #pragma unroll
    for (int r = 0; r < 4; ++r) {
        const float inv = 1.0f / lacc[r];
        float* orow = O + boff + (size_t)(qb + quad * 4 + r) * D_ + l15;
        #pragma unroll
        for (int d = 0; d < 4; ++d) orow[d * 16] = ofr[d][r] * inv;
    }
}

extern "C" void kernel_launch(void* const* d_in, const int* in_sizes, int n_in,
                              void* d_out, int out_size, void* d_ws, size_t ws_size,
                              hipStream_t stream) {
    const float* Q = (const float*)d_in[0];
    const float* K = (const float*)d_in[1];
    const float* V = (const float*)d_in[2];
    float* O = (float*)d_out;

    if (ws_size >= (size_t)8 * 1024 * 1024) {
        _Float16* K16F  = (_Float16*)d_ws;                             // 2 MB
        _Float16* VT16F = K16F + (size_t)1048576;                      // 2 MB
        prepass_frag<<<1024, NT, 0, stream>>>(K, V, K16F, VT16F);
        attn_dsplit2<<<256, 1024, 0, stream>>>(Q, K16F, VT16F, O);
    } else {
        attn_mfma_f16<<<256, NT, 0, stream>>>(Q, K, V, O);
    }
}